// Round 4
// baseline (14218.782 us; speedup 1.0000x reference)
//
#include <hip/hip_runtime.h>
#include <cstdint>

// ---------------------------------------------------------------------------
// MultiHeadAttention (B=8,S=1024,D=1024,H=16,E=64).
// Inputs fp32; OUTPUT fp32 (reference returns float32 — R3 wrongly stored
// bf16 u16s; the "(bf16, ...)" in the harness message is a hard-coded label).
// Quirks: scale = 1/sqrt(8) (d_k = batch quirk); tril + exact-zero -> -1e9;
// softmax over the HEADS axis (local per (b,q,k)); per-element v/sum.
// R4 = R3 with the final GEMM storing fp32 to d_out. No other changes.
// ---------------------------------------------------------------------------

typedef unsigned short u16;
typedef unsigned int   u32;

#define S_ 1024
#define D_ 1024
#define H_ 16
#define E_ 64

__device__ __forceinline__ u16 f2b(float f) {      // round-to-nearest-even
  union { float f; u32 u; } v; v.f = f;
  u32 r = v.u + 0x7fffu + ((v.u >> 16) & 1u);
  return (u16)(r >> 16);
}

// ---------------------------------------------------------------------------
// fp32 GEMM: C[M][N] = A[M][K] @ W[K][N] + bias[N].
// 128x128 tile, BK=8, 256 threads, each thread 8x8 outputs. out_bf16 selects
// u16 (RNE) vs float stores.
// ---------------------------------------------------------------------------
__global__ __launch_bounds__(256, 2) void gemm_f32(
    const float* __restrict__ A, const float* __restrict__ W,
    const float* __restrict__ bias, void* __restrict__ Cv,
    int M, int N, int K, int out_bf16)
{
  __shared__ float As[8][128];   // [k][m] 4KB
  __shared__ float Ws[8][128];   // [k][n] 4KB
  const int t  = threadIdx.x;
  const int ty = t >> 4, tx = t & 15;
  const int m_base = blockIdx.x * 128;
  const int n_base = blockIdx.y * 128;

  float acc[8][8];
#pragma unroll
  for (int i = 0; i < 8; ++i)
#pragma unroll
    for (int j = 0; j < 8; ++j) acc[i][j] = 0.f;

  const int am = t >> 1;          // 0..127 (A row in tile)
  const int ak = (t & 1) * 4;     // 0 or 4
  const int wk = t >> 5;          // 0..7  (W k-row in tile)
  const int wn = (t & 31) * 4;    // 0..124
  const float* Arow = A + (size_t)(m_base + am) * K + ak;
  const float* Wrow = W + (size_t)wk * N + n_base + wn;

  for (int kb = 0; kb < K; kb += 8) {
    __syncthreads();
    float4 av = *(const float4*)(Arow + kb);
    float4 wv = *(const float4*)(Wrow + (size_t)kb * N);
    As[ak + 0][am] = av.x; As[ak + 1][am] = av.y;
    As[ak + 2][am] = av.z; As[ak + 3][am] = av.w;
    *(float4*)&Ws[wk][wn] = wv;
    __syncthreads();
#pragma unroll
    for (int kk = 0; kk < 8; ++kk) {
      float a[8], b[8];
      *(float4*)&a[0] = *(const float4*)&As[kk][ty * 8];
      *(float4*)&a[4] = *(const float4*)&As[kk][ty * 8 + 4];
      *(float4*)&b[0] = *(const float4*)&Ws[kk][tx * 8];
      *(float4*)&b[4] = *(const float4*)&Ws[kk][tx * 8 + 4];
#pragma unroll
      for (int i = 0; i < 8; ++i)
#pragma unroll
        for (int j = 0; j < 8; ++j) acc[i][j] = fmaf(a[i], b[j], acc[i][j]);
    }
  }

  float bv[8];
#pragma unroll
  for (int j = 0; j < 8; ++j) bv[j] = bias[n_base + tx * 8 + j];

  if (out_bf16) {
    u16* C = (u16*)Cv;
#pragma unroll
    for (int i = 0; i < 8; ++i) {
      size_t ro = (size_t)(m_base + ty * 8 + i) * N + n_base + tx * 8;
#pragma unroll
      for (int j = 0; j < 8; ++j) C[ro + j] = f2b(acc[i][j] + bv[j]);
    }
  } else {
    float* C = (float*)Cv;
#pragma unroll
    for (int i = 0; i < 8; ++i) {
      size_t ro = (size_t)(m_base + ty * 8 + i) * N + n_base + tx * 8;
      float4 c0 = {acc[i][0] + bv[0], acc[i][1] + bv[1],
                   acc[i][2] + bv[2], acc[i][3] + bv[3]};
      float4 c1 = {acc[i][4] + bv[4], acc[i][5] + bv[5],
                   acc[i][6] + bv[6], acc[i][7] + bv[7]};
      *(float4*)(C + ro) = c0;
      *(float4*)(C + ro + 4) = c1;
    }
  }
}

// ---------------------------------------------------------------------------
// Fused attention, softmax over HEADS, all fp32.
// Grid (32,8) = (q-tile of 32, batch). Block 1024 = 16 waves; wave h = head h.
// Tk=8 per iteration (128 iters).
// LDS: Ks 16*8*68*4 = 34.8KB, Sc 16*289*4 = 18.5KB  -> 53.3KB (<64KB).
// ---------------------------------------------------------------------------
#define KS_K 68          // padded k-row stride (floats)
#define KS_H (8 * KS_K)  // per-head stride
#define SC_Q 9           // padded q-stride (floats)
#define SC_H (32 * SC_Q + 1)  // per-head stride (odd -> conflict-free h-walk)

__global__ __launch_bounds__(1024, 1) void attn_headsoftmax_f32(
    const float* __restrict__ Qf,  // [B][S][D]
    const float* __restrict__ Kf,  // [B][S][D]
    const float* __restrict__ Vf,  // [B][S][D]
    float* __restrict__ AO)        // [B][S][D]
{
  const int qt   = blockIdx.x;
  const int b    = blockIdx.y;
  const int tid  = threadIdx.x;
  const int h    = tid >> 6;
  const int lane = tid & 63;
  const int q    = lane >> 1;      // 0..31
  const int half = lane & 1;       // e-half
  const int e0   = half * 32;
  const int q0   = qt * 32;

  __shared__ float Ks[16 * KS_H];
  __shared__ float Sc[16 * SC_H];

  // Q rows resident in registers: Q[b][q0+q][h*64 + e0 .. +32]
  float Qr[32];
  {
    const float* Qp = Qf + ((size_t)(b * S_ + q0 + q)) * D_ + h * E_ + e0;
#pragma unroll
    for (int c = 0; c < 8; ++c) {
      float4 v = *(const float4*)(Qp + c * 4);
      Qr[c * 4 + 0] = v.x; Qr[c * 4 + 1] = v.y;
      Qr[c * 4 + 2] = v.z; Qr[c * 4 + 3] = v.w;
    }
  }
  float Oc[32];
#pragma unroll
  for (int i = 0; i < 32; ++i) Oc[i] = 0.f;

  const float rsq8 = sqrtf(8.0f);  // matches np.sqrt(float32(8))

  for (int kt = 0; kt < 128; ++kt) {
    const int k0 = kt * 8;
    {  // ---- stage K tile: wave h loads K[b][k0..k0+8)[h*64..+64) ----
      const int kk = lane >> 3;           // 0..7
      const int ec = (lane & 7) * 8;      // 0..56
      const float* Kp = Kf + ((size_t)(b * S_ + k0 + kk)) * D_ + h * E_ + ec;
      float* Kd = &Ks[h * KS_H + kk * KS_K + ec];
      *(float4*)(Kd)     = *(const float4*)(Kp);
      *(float4*)(Kd + 4) = *(const float4*)(Kp + 4);
    }
    __syncthreads();
    {  // ---- scores ----
      float part[8];
#pragma unroll
      for (int kk = 0; kk < 8; ++kk) {
        const float* Kr = &Ks[h * KS_H + kk * KS_K + e0];
        float dot = 0.f;
#pragma unroll
        for (int c = 0; c < 8; ++c) {
          float4 kv = *(const float4*)(Kr + c * 4);
          dot = fmaf(Qr[c * 4 + 0], kv.x, dot);
          dot = fmaf(Qr[c * 4 + 1], kv.y, dot);
          dot = fmaf(Qr[c * 4 + 2], kv.z, dot);
          dot = fmaf(Qr[c * 4 + 3], kv.w, dot);
        }
        part[kk] = dot;
      }
#pragma unroll
      for (int kk = 0; kk < 8; ++kk) {
        float tot = part[kk] + __shfl_xor(part[kk], 1);
        float s = tot / rsq8;
        // tril mask (index) OR exact-zero in lower tri -> -1e9 (source quirk)
        if ((k0 + kk > q0 + q) || (s == 0.0f)) s = -1e9f;
        if ((kk >> 2) == half)  // half 0 writes kk 0..3, half 1 -> 4..7
          Sc[h * SC_H + q * SC_Q + kk] = s;
      }
    }
    __syncthreads();
    if (tid < 256) {  // ---- softmax over heads at (q2,k2) ----
      const int q2 = tid >> 3, k2 = tid & 7;
      const int base = q2 * SC_Q + k2;
      float v[16];
      float m = -3.0e38f;
#pragma unroll
      for (int hh = 0; hh < 16; ++hh) {
        v[hh] = Sc[hh * SC_H + base];
        m = fmaxf(m, v[hh]);
      }
      float sum = 0.f;
#pragma unroll
      for (int hh = 0; hh < 16; ++hh) { v[hh] = expf(v[hh] - m); sum += v[hh]; }
#pragma unroll
      for (int hh = 0; hh < 16; ++hh) Sc[hh * SC_H + base] = v[hh] / sum;
    }
    __syncthreads();
    {  // ---- PV: O[q][e0..e0+32) += attn[q][k] * V[k][e0..] ----
#pragma unroll
      for (int kk = 0; kk < 8; ++kk) {
        float at = Sc[h * SC_H + q * SC_Q + kk];
        const float* Vp = Vf + ((size_t)(b * S_ + k0 + kk)) * D_ + h * E_ + e0;
#pragma unroll
        for (int c = 0; c < 8; ++c) {
          float4 vv = *(const float4*)(Vp + c * 4);
          Oc[c * 4 + 0] = fmaf(at, vv.x, Oc[c * 4 + 0]);
          Oc[c * 4 + 1] = fmaf(at, vv.y, Oc[c * 4 + 1]);
          Oc[c * 4 + 2] = fmaf(at, vv.z, Oc[c * 4 + 2]);
          Oc[c * 4 + 3] = fmaf(at, vv.w, Oc[c * 4 + 3]);
        }
      }
    }
    __syncthreads();  // protect Ks/Sc before next iteration
  }

  float* Op = AO + ((size_t)(b * S_ + q0 + q)) * D_ + h * E_ + e0;
#pragma unroll
  for (int c = 0; c < 8; ++c) {
    float4 v = {Oc[c * 4 + 0], Oc[c * 4 + 1], Oc[c * 4 + 2], Oc[c * 4 + 3]};
    *(float4*)(Op + c * 4) = v;
  }
}

// ---------------------------------------------------------------------------
extern "C" void kernel_launch(void* const* d_in, const int* in_sizes, int n_in,
                              void* d_out, int out_size, void* d_ws,
                              size_t ws_size, hipStream_t stream)
{
  const float* X1 = (const float*)d_in[0];
  const float* X2 = (const float*)d_in[1];
  const float* Wq = (const float*)d_in[2];
  const float* bq = (const float*)d_in[3];
  const float* Wk = (const float*)d_in[4];
  const float* bk = (const float*)d_in[5];
  const float* Wv = (const float*)d_in[6];
  const float* bv = (const float*)d_in[7];
  const float* Wo = (const float*)d_in[8];
  const float* bo = (const float*)d_in[9];

  // Workspace (fp32): Q, K, V, AO @ 8M floats (32MB) each = 128MB.
  float* Qf  = (float*)d_ws;
  float* Kf  = Qf + (8u << 20);
  float* Vf  = Kf + (8u << 20);
  float* AOf = Vf + (8u << 20);

  dim3 gg(64, 8);  // (M/128, N/128)
  gemm_f32<<<gg, 256, 0, stream>>>(X1, Wq, bq, Qf, 8192, 1024, 1024, 0);
  gemm_f32<<<gg, 256, 0, stream>>>(X2, Wk, bk, Kf, 8192, 1024, 1024, 0);
  gemm_f32<<<gg, 256, 0, stream>>>(X2, Wv, bv, Vf, 8192, 1024, 1024, 0);

  attn_headsoftmax_f32<<<dim3(32, 8), 1024, 0, stream>>>(Qf, Kf, Vf, AOf);

  // Output is FLOAT32 (reference returns fp32) — store floats to d_out.
  gemm_f32<<<gg, 256, 0, stream>>>(AOf, Wo, bo, d_out, 8192, 1024, 1024, 0);
}

// Round 5
// 1220.126 us; speedup vs baseline: 11.6535x; 11.6535x over previous
//
#include <hip/hip_runtime.h>
#include <cstdint>

// ---------------------------------------------------------------------------
// MultiHeadAttention (B=8,S=1024,D=1024,H=16,E=64). Inputs fp32, output fp32.
// Quirks: scale = 1/sqrt(8) (d_k = batch quirk); tril + exact-zero -> -1e9
// (checked in fp32 BEFORE any bf16 rounding, matching ref order);
// softmax over the HEADS axis (local per (b,q,k)); per-element v/sum.
//
// R5: attention rebuilt on bf16 MFMA (R4's fp32 version spilled: VGPR=64,
// 18 GB scratch writes, 13.6 ms). QKV GEMMs emit bf16; V transposed per-head;
// fused attn: QK^T MFMA -> fp32 mask -> bf16 scores LDS -> head-softmax ->
// PV MFMA -> fp32 O. Final output GEMM stays fp32 (validated path).
// ---------------------------------------------------------------------------

typedef unsigned short u16;
typedef unsigned int   u32;
typedef __attribute__((ext_vector_type(8))) __bf16         bf16x8;
typedef __attribute__((ext_vector_type(8))) unsigned short ushort8;
typedef __attribute__((ext_vector_type(4))) float          f32x4;

#define S_ 1024
#define D_ 1024
#define H_ 16
#define E_ 64

__device__ __forceinline__ float b2f(u16 h) {
  union { u32 u; float f; } v; v.u = ((u32)h) << 16; return v.f;
}
__device__ __forceinline__ u16 f2b(float f) {      // round-to-nearest-even
  union { float f; u32 u; } v; v.f = f;
  u32 r = v.u + 0x7fffu + ((v.u >> 16) & 1u);
  return (u16)(r >> 16);
}

// ---------------------------------------------------------------------------
// fp32 GEMM: C[M][N] = A[M][K] @ W[K][N] + bias[N].
// 128x128 tile, BK=8, 256 threads, each thread 8x8 outputs.
// out_bf16: 1 -> u16 RNE stores, 0 -> float4 stores.
// ---------------------------------------------------------------------------
__global__ __launch_bounds__(256, 2) void gemm_f32(
    const float* __restrict__ A, const float* __restrict__ W,
    const float* __restrict__ bias, void* __restrict__ Cv,
    int M, int N, int K, int out_bf16)
{
  __shared__ float As[8][128];   // [k][m] 4KB
  __shared__ float Ws[8][128];   // [k][n] 4KB
  const int t  = threadIdx.x;
  const int ty = t >> 4, tx = t & 15;
  const int m_base = blockIdx.x * 128;
  const int n_base = blockIdx.y * 128;

  float acc[8][8];
#pragma unroll
  for (int i = 0; i < 8; ++i)
#pragma unroll
    for (int j = 0; j < 8; ++j) acc[i][j] = 0.f;

  const int am = t >> 1;          // 0..127 (A row in tile)
  const int ak = (t & 1) * 4;     // 0 or 4
  const int wk = t >> 5;          // 0..7  (W k-row in tile)
  const int wn = (t & 31) * 4;    // 0..124
  const float* Arow = A + (size_t)(m_base + am) * K + ak;
  const float* Wrow = W + (size_t)wk * N + n_base + wn;

  for (int kb = 0; kb < K; kb += 8) {
    __syncthreads();
    float4 av = *(const float4*)(Arow + kb);
    float4 wv = *(const float4*)(Wrow + (size_t)kb * N);
    As[ak + 0][am] = av.x; As[ak + 1][am] = av.y;
    As[ak + 2][am] = av.z; As[ak + 3][am] = av.w;
    *(float4*)&Ws[wk][wn] = wv;
    __syncthreads();
#pragma unroll
    for (int kk = 0; kk < 8; ++kk) {
      float a[8], b[8];
      *(float4*)&a[0] = *(const float4*)&As[kk][ty * 8];
      *(float4*)&a[4] = *(const float4*)&As[kk][ty * 8 + 4];
      *(float4*)&b[0] = *(const float4*)&Ws[kk][tx * 8];
      *(float4*)&b[4] = *(const float4*)&Ws[kk][tx * 8 + 4];
#pragma unroll
      for (int i = 0; i < 8; ++i)
#pragma unroll
        for (int j = 0; j < 8; ++j) acc[i][j] = fmaf(a[i], b[j], acc[i][j]);
    }
  }

  float bv[8];
#pragma unroll
  for (int j = 0; j < 8; ++j) bv[j] = bias[n_base + tx * 8 + j];

  if (out_bf16) {
    u16* C = (u16*)Cv;
#pragma unroll
    for (int i = 0; i < 8; ++i) {
      size_t ro = (size_t)(m_base + ty * 8 + i) * N + n_base + tx * 8;
      ushort8 pk;
#pragma unroll
      for (int j = 0; j < 8; ++j) pk[j] = f2b(acc[i][j] + bv[j]);
      *(ushort8*)(C + ro) = pk;
    }
  } else {
    float* C = (float*)Cv;
#pragma unroll
    for (int i = 0; i < 8; ++i) {
      size_t ro = (size_t)(m_base + ty * 8 + i) * N + n_base + tx * 8;
      float4 c0 = {acc[i][0] + bv[0], acc[i][1] + bv[1],
                   acc[i][2] + bv[2], acc[i][3] + bv[3]};
      float4 c1 = {acc[i][4] + bv[4], acc[i][5] + bv[5],
                   acc[i][6] + bv[6], acc[i][7] + bv[7]};
      *(float4*)(C + ro) = c0;
      *(float4*)(C + ro + 4) = c1;
    }
  }
}

// ---------------------------------------------------------------------------
// V transpose (bf16): V[b][s][h*64+e] -> Vt[(b*16+h)*64+e][s]  (per-head E,S)
// ---------------------------------------------------------------------------
__global__ __launch_bounds__(256, 1) void transpose_v(
    const u16* __restrict__ V, u16* __restrict__ Vt)
{
  __shared__ u16 t[64][72];
  const int s0 = blockIdx.x * 64;
  const int bh = blockIdx.y;           // b*16 + h
  const int b = bh >> 4, h = bh & 15;
  const int row = threadIdx.x >> 3;
  const int cs  = (threadIdx.x & 7) * 8;
#pragma unroll
  for (int p = 0; p < 2; ++p) {
    int s = row + p * 32;
    *(ushort8*)(&t[s][cs]) = *(const ushort8*)(
        V + ((size_t)(b * S_ + s0 + s)) * D_ + h * E_ + cs);
  }
  __syncthreads();
#pragma unroll
  for (int p = 0; p < 2; ++p) {
    int e = row + p * 32;
    ushort8 v;
#pragma unroll
    for (int i = 0; i < 8; ++i) v[i] = t[cs + i][e];
    *(ushort8*)(Vt + ((size_t)(bh * E_ + e)) * S_ + s0 + cs) = v;
  }
}

// ---------------------------------------------------------------------------
// Fused attention, softmax over HEADS, bf16 MFMA.
// Grid (32,8) = (q-tile of 32, batch). Block 1024 = 16 waves; wave h = head h.
// Per kt (32 iters of Tk=32): QK^T (8 MFMA) -> fp32 scale/mask -> bf16 scores
// to LDS -> barrier -> per-(q,k) softmax across 16 h-planes (1024 threads,
// thread-private columns) -> barrier -> PV (8 MFMA; attn A-frags from LDS,
// V^T B-frags from global) -> barrier. O accumulates fp32; stored fp32.
// ---------------------------------------------------------------------------
__global__ __launch_bounds__(1024, 4) void attn_headsoftmax(
    const u16* __restrict__ Qg,   // [B][S][D] bf16
    const u16* __restrict__ Kg,   // [B][S][D] bf16
    const u16* __restrict__ Vt,   // [B*H][E][S] bf16
    float* __restrict__ AO)       // [B][S][D] fp32
{
  const int qt   = blockIdx.x;
  const int b    = blockIdx.y;
  const int tid  = threadIdx.x;
  const int h    = tid >> 6;
  const int lane = tid & 63;
  const int quad = lane >> 4;
  const int l16  = lane & 15;
  const int q0   = qt * 32;

  __shared__ u16 sc[16][32][40];  // 40KB; scores then (in-place) attn, bf16

  // Q A-frags, resident all kernel: [m-chunk][e-chunk]
  bf16x8 qf[2][2];
  {
    const u16* Qb = Qg + ((size_t)(b * S_ + q0)) * D_ + h * E_;
#pragma unroll
    for (int i = 0; i < 2; ++i)
#pragma unroll
      for (int c = 0; c < 2; ++c)
        qf[i][c] = *(const bf16x8*)(Qb + (size_t)(i * 16 + l16) * D_ +
                                    c * 32 + quad * 8);
  }

  f32x4 oacc[2][4];  // O[m-chunk(16q)][e-chunk(16e)]
#pragma unroll
  for (int i = 0; i < 2; ++i)
#pragma unroll
    for (int nc = 0; nc < 4; ++nc) oacc[i][nc] = (f32x4){0.f, 0.f, 0.f, 0.f};

  const float rsq8 = sqrtf(8.0f);   // true division to match np

  for (int kt = 0; kt < 32; ++kt) {
    const int k0 = kt * 32;
    {  // ---- scores = Q K^T / sqrt(8), mask, -> LDS bf16 ----
      const u16* Kb = Kg + ((size_t)(b * S_ + k0)) * D_ + h * E_;
      bf16x8 kf[2][2];  // B-frag: n=kcol (lane&15), k=e (quad*8+j)
#pragma unroll
      for (int nc = 0; nc < 2; ++nc)
#pragma unroll
        for (int c = 0; c < 2; ++c)
          kf[nc][c] = *(const bf16x8*)(Kb + (size_t)(nc * 16 + l16) * D_ +
                                       c * 32 + quad * 8);
      f32x4 sacc[2][2];
#pragma unroll
      for (int i = 0; i < 2; ++i)
#pragma unroll
        for (int nc = 0; nc < 2; ++nc) sacc[i][nc] = (f32x4){0.f,0.f,0.f,0.f};
#pragma unroll
      for (int c = 0; c < 2; ++c)
#pragma unroll
        for (int i = 0; i < 2; ++i)
#pragma unroll
          for (int nc = 0; nc < 2; ++nc)
            sacc[i][nc] = __builtin_amdgcn_mfma_f32_16x16x32_bf16(
                qf[i][c], kf[nc][c], sacc[i][nc], 0, 0, 0);
#pragma unroll
      for (int i = 0; i < 2; ++i)
#pragma unroll
        for (int nc = 0; nc < 2; ++nc)
#pragma unroll
          for (int reg = 0; reg < 4; ++reg) {
            int qrow = i * 16 + quad * 4 + reg;  // C: row=quad*4+reg
            int kcol = nc * 16 + l16;            // C: col=lane&15
            float s = sacc[i][nc][reg] / rsq8;
            // tril (index) OR exact-zero in lower tri -> -1e9 (fp32, pre-round)
            if ((k0 + kcol > q0 + qrow) || (s == 0.0f)) s = -1e9f;
            sc[h][qrow][kcol] = f2b(s);
          }
    }
    __syncthreads();
    {  // ---- softmax across the 16 heads at this thread's (q,k) ----
      const int qq = tid >> 5, kk = tid & 31;
      float v[16];
      float m = -3.0e38f;
#pragma unroll
      for (int hh = 0; hh < 16; ++hh) {
        v[hh] = b2f(sc[hh][qq][kk]);
        m = fmaxf(m, v[hh]);
      }
      float sum = 0.f;
#pragma unroll
      for (int hh = 0; hh < 16; ++hh) { v[hh] = expf(v[hh] - m); sum += v[hh]; }
#pragma unroll
      for (int hh = 0; hh < 16; ++hh) sc[hh][qq][kk] = f2b(v[hh] / sum);
    }
    __syncthreads();
    {  // ---- O += attn @ V  (A-frags from LDS, B-frags from global V^T) ----
      bf16x8 af[2];
#pragma unroll
      for (int i = 0; i < 2; ++i)  // A: m=q (lane&15), k (quad*8+j)
        af[i] = *(const bf16x8*)(&sc[h][i * 16 + l16][quad * 8]);
      const u16* Vb = Vt + ((size_t)((b * H_ + h) * E_)) * S_ + k0;
      bf16x8 vf[4];
#pragma unroll
      for (int nc = 0; nc < 4; ++nc)  // B: n=e (lane&15), k=s (quad*8+j)
        vf[nc] = *(const bf16x8*)(Vb + (size_t)(nc * 16 + l16) * S_ + quad * 8);
#pragma unroll
      for (int i = 0; i < 2; ++i)
#pragma unroll
        for (int nc = 0; nc < 4; ++nc)
          oacc[i][nc] = __builtin_amdgcn_mfma_f32_16x16x32_bf16(
              af[i], vf[nc], oacc[i][nc], 0, 0, 0);
    }
    __syncthreads();  // protect sc before next iter's score stores
  }

  float* Ob = AO + ((size_t)(b * S_ + q0)) * D_ + h * E_;
#pragma unroll
  for (int i = 0; i < 2; ++i)
#pragma unroll
    for (int nc = 0; nc < 4; ++nc)
#pragma unroll
      for (int reg = 0; reg < 4; ++reg) {
        int qrow = i * 16 + quad * 4 + reg;
        int e    = nc * 16 + l16;
        Ob[(size_t)qrow * D_ + e] = oacc[i][nc][reg];
      }
}

// ---------------------------------------------------------------------------
extern "C" void kernel_launch(void* const* d_in, const int* in_sizes, int n_in,
                              void* d_out, int out_size, void* d_ws,
                              size_t ws_size, hipStream_t stream)
{
  const float* X1 = (const float*)d_in[0];
  const float* X2 = (const float*)d_in[1];
  const float* Wq = (const float*)d_in[2];
  const float* bq = (const float*)d_in[3];
  const float* Wk = (const float*)d_in[4];
  const float* bk = (const float*)d_in[5];
  const float* Wv = (const float*)d_in[6];
  const float* bv = (const float*)d_in[7];
  const float* Wo = (const float*)d_in[8];
  const float* bo = (const float*)d_in[9];

  // Workspace: Qb,Kb,Vb,Vt bf16 (16 MB each) + AO fp32 (32 MB) = 96 MB.
  u16*   Qb  = (u16*)d_ws;
  u16*   Kb  = Qb + (8u << 20);
  u16*   Vb  = Kb + (8u << 20);
  u16*   Vtb = Vb + (8u << 20);
  float* AOf = (float*)(Vtb + (8u << 20));

  dim3 gg(64, 8);  // (M/128, N/128)
  gemm_f32<<<gg, 256, 0, stream>>>(X1, Wq, bq, Qb, 8192, 1024, 1024, 1);
  gemm_f32<<<gg, 256, 0, stream>>>(X2, Wk, bk, Kb, 8192, 1024, 1024, 1);
  gemm_f32<<<gg, 256, 0, stream>>>(X2, Wv, bv, Vb, 8192, 1024, 1024, 1);

  transpose_v<<<dim3(16, 128), 256, 0, stream>>>(Vb, Vtb);

  attn_headsoftmax<<<dim3(32, 8), 1024, 0, stream>>>(Qb, Kb, Vtb, AOf);

  // Output fp32 (reference returns float32).
  gemm_f32<<<gg, 256, 0, stream>>>(AOf, Wo, bo, d_out, 8192, 1024, 1024, 0);
}

// Round 6
// 532.881 us; speedup vs baseline: 26.6829x; 2.2897x over previous
//
#include <hip/hip_runtime.h>
#include <cstdint>

// ---------------------------------------------------------------------------
// MultiHeadAttention (B=8,S=1024,D=1024,H=16,E=64). Inputs fp32, output fp32.
// Quirks: scale = 1/sqrt(8) (d_k = batch quirk); tril + exact-zero -> -1e9
// (fp32, pre-bf16-round); softmax over HEADS axis (local per (b,q,k)).
//
// R6: all four GEMMs moved to bf16 MFMA (R5 profile: 4 fp32 GEMMs ~900us of
// 1220us at 75 TF; bf16 MFMA is ~8x that rate). Fragment maps identical to
// the R5-validated attention MFMAs. X1/X2 pre-converted to bf16; weights
// transpose+converted to Wt[N][K] bf16; attention emits bf16 AO; final GEMM
// stores fp32. Attention kernel otherwise unchanged from R5.
// ---------------------------------------------------------------------------

typedef unsigned short u16;
typedef unsigned int   u32;
typedef __attribute__((ext_vector_type(8))) __bf16         bf16x8;
typedef __attribute__((ext_vector_type(8))) unsigned short ushort8;
typedef __attribute__((ext_vector_type(4))) float          f32x4;

#define S_ 1024
#define D_ 1024
#define H_ 16
#define E_ 64

__device__ __forceinline__ float b2f(u16 h) {
  union { u32 u; float f; } v; v.u = ((u32)h) << 16; return v.f;
}
__device__ __forceinline__ u16 f2b(float f) {      // round-to-nearest-even
  union { float f; u32 u; } v; v.f = f;
  u32 r = v.u + 0x7fffu + ((v.u >> 16) & 1u);
  return (u16)(r >> 16);
}

// ---------------------------------------------------------------------------
// fp32 -> bf16 elementwise convert. n must be a multiple of 2048 (grid-exact).
// ---------------------------------------------------------------------------
__global__ __launch_bounds__(256, 1) void cvt_bf16(
    const float* __restrict__ src, u16* __restrict__ dst)
{
  const size_t i = (size_t)blockIdx.x * 256 + threadIdx.x;
  float4 a = ((const float4*)src)[2 * i];
  float4 b = ((const float4*)src)[2 * i + 1];
  ushort8 o;
  o[0] = f2b(a.x); o[1] = f2b(a.y); o[2] = f2b(a.z); o[3] = f2b(a.w);
  o[4] = f2b(b.x); o[5] = f2b(b.y); o[6] = f2b(b.z); o[7] = f2b(b.w);
  ((ushort8*)dst)[i] = o;
}

// ---------------------------------------------------------------------------
// Weight transpose+convert: W fp32 [K][N] -> Wt bf16 [N][K]. 64x64 tiles.
// Same structure as the R5-validated transpose_v.
// ---------------------------------------------------------------------------
__global__ __launch_bounds__(256, 1) void trans_cvt_w(
    const float* __restrict__ W, u16* __restrict__ Wt)
{
  __shared__ u16 t[64][72];
  const int k0 = blockIdx.x * 64, n0 = blockIdx.y * 64;
  const int row = threadIdx.x >> 3;
  const int cs  = (threadIdx.x & 7) * 8;
#pragma unroll
  for (int p = 0; p < 2; ++p) {
    int r = row + p * 32;
    const float* Wp = W + (size_t)(k0 + r) * 1024 + n0 + cs;
    float4 a = *(const float4*)(Wp);
    float4 b = *(const float4*)(Wp + 4);
    u16* tp = &t[r][cs];
    tp[0] = f2b(a.x); tp[1] = f2b(a.y); tp[2] = f2b(a.z); tp[3] = f2b(a.w);
    tp[4] = f2b(b.x); tp[5] = f2b(b.y); tp[6] = f2b(b.z); tp[7] = f2b(b.w);
  }
  __syncthreads();
#pragma unroll
  for (int p = 0; p < 2; ++p) {
    int n = row + p * 32;
    ushort8 v;
#pragma unroll
    for (int i = 0; i < 8; ++i) v[i] = t[cs + i][n];
    *(ushort8*)(Wt + (size_t)(n0 + n) * 1024 + k0 + cs) = v;
  }
}

// ---------------------------------------------------------------------------
// bf16 MFMA GEMM: C[M][N] = A[M][K] @ Bt[N][K]^T + bias[N] (fp32 accum).
// 128x128 tile, BK=32, 256 threads / 4 waves, each wave 64x64 via 4x4 accs.
// out_f32: 1 -> fp32 stores (final output), 0 -> bf16 u16 stores.
// Fragment maps validated by R5's attention kernel.
// ---------------------------------------------------------------------------
__global__ __launch_bounds__(256, 1) void gemm_bf16(
    const u16* __restrict__ A, const u16* __restrict__ Bt,
    const float* __restrict__ bias, void* __restrict__ Cv,
    int M, int N, int K, int out_f32)
{
  __shared__ u16 As[128 * 32];   // [m][k] row-major, 8KB
  __shared__ u16 Bs[128 * 32];   // [n][k] row-major, 8KB
  const int tid  = threadIdx.x;
  const int wave = tid >> 6;
  const int lane = tid & 63;
  const int quad = lane >> 4;
  const int l16  = lane & 15;
  const int m0   = (wave & 1) * 64;
  const int n0   = (wave >> 1) * 64;

  const u16* Ab = A  + (size_t)blockIdx.x * 128 * K;
  const u16* Bb = Bt + (size_t)blockIdx.y * 128 * K;

  f32x4 acc[4][4];
#pragma unroll
  for (int i = 0; i < 4; ++i)
#pragma unroll
    for (int j = 0; j < 4; ++j) acc[i][j] = (f32x4){0.f, 0.f, 0.f, 0.f};

  for (int kb = 0; kb < K; kb += 32) {
    __syncthreads();               // prior iter's LDS reads done
#pragma unroll
    for (int p = 0; p < 2; ++p) {  // 512 16B segs over 256 threads
      int seg = tid + p * 256;
      int row = seg >> 2, ks = seg & 3;
      ushort8 va = *(const ushort8*)(Ab + (size_t)row * K + kb + ks * 8);
      ushort8 vb = *(const ushort8*)(Bb + (size_t)row * K + kb + ks * 8);
      *(ushort8*)(As + seg * 8) = va;
      *(ushort8*)(Bs + seg * 8) = vb;
    }
    __syncthreads();

    bf16x8 af[4], bfr[4];
#pragma unroll
    for (int i = 0; i < 4; ++i)    // A-frag: m=lane&15, k=quad*8+j
      af[i] = *(const bf16x8*)(As + (m0 + i * 16 + l16) * 32 + quad * 8);
#pragma unroll
    for (int j = 0; j < 4; ++j)    // B-frag: n=lane&15, k=quad*8+j
      bfr[j] = *(const bf16x8*)(Bs + (n0 + j * 16 + l16) * 32 + quad * 8);
#pragma unroll
    for (int i = 0; i < 4; ++i)
#pragma unroll
      for (int j = 0; j < 4; ++j)
        acc[i][j] = __builtin_amdgcn_mfma_f32_16x16x32_bf16(
            af[i], bfr[j], acc[i][j], 0, 0, 0);
  }

  float bv[4];
#pragma unroll
  for (int j = 0; j < 4; ++j)
    bv[j] = bias[(size_t)blockIdx.y * 128 + n0 + j * 16 + l16];

  if (out_f32) {
    float* C = (float*)Cv;
#pragma unroll
    for (int i = 0; i < 4; ++i) {
      int r = blockIdx.x * 128 + m0 + i * 16 + quad * 4;   // row=quad*4+reg
#pragma unroll
      for (int j = 0; j < 4; ++j) {
        int c = blockIdx.y * 128 + n0 + j * 16 + l16;      // col=lane&15
#pragma unroll
        for (int reg = 0; reg < 4; ++reg)
          C[(size_t)(r + reg) * N + c] = acc[i][j][reg] + bv[j];
      }
    }
  } else {
    u16* C = (u16*)Cv;
#pragma unroll
    for (int i = 0; i < 4; ++i) {
      int r = blockIdx.x * 128 + m0 + i * 16 + quad * 4;
#pragma unroll
      for (int j = 0; j < 4; ++j) {
        int c = blockIdx.y * 128 + n0 + j * 16 + l16;
#pragma unroll
        for (int reg = 0; reg < 4; ++reg)
          C[(size_t)(r + reg) * N + c] = f2b(acc[i][j][reg] + bv[j]);
      }
    }
  }
}

// ---------------------------------------------------------------------------
// V transpose (bf16): V[b][s][h*64+e] -> Vt[(b*16+h)*64+e][s]  (per-head E,S)
// ---------------------------------------------------------------------------
__global__ __launch_bounds__(256, 1) void transpose_v(
    const u16* __restrict__ V, u16* __restrict__ Vt)
{
  __shared__ u16 t[64][72];
  const int s0 = blockIdx.x * 64;
  const int bh = blockIdx.y;           // b*16 + h
  const int b = bh >> 4, h = bh & 15;
  const int row = threadIdx.x >> 3;
  const int cs  = (threadIdx.x & 7) * 8;
#pragma unroll
  for (int p = 0; p < 2; ++p) {
    int s = row + p * 32;
    *(ushort8*)(&t[s][cs]) = *(const ushort8*)(
        V + ((size_t)(b * S_ + s0 + s)) * D_ + h * E_ + cs);
  }
  __syncthreads();
#pragma unroll
  for (int p = 0; p < 2; ++p) {
    int e = row + p * 32;
    ushort8 v;
#pragma unroll
    for (int i = 0; i < 8; ++i) v[i] = t[cs + i][e];
    *(ushort8*)(Vt + ((size_t)(bh * E_ + e)) * S_ + s0 + cs) = v;
  }
}

// ---------------------------------------------------------------------------
// Fused attention, softmax over HEADS, bf16 MFMA (structure = R5, validated).
// Only change: epilogue stores bf16 (feeds the bf16 output GEMM).
// ---------------------------------------------------------------------------
__global__ __launch_bounds__(1024, 4) void attn_headsoftmax(
    const u16* __restrict__ Qg,   // [B][S][D] bf16
    const u16* __restrict__ Kg,   // [B][S][D] bf16
    const u16* __restrict__ Vt,   // [B*H][E][S] bf16
    u16* __restrict__ AO)         // [B][S][D] bf16
{
  const int qt   = blockIdx.x;
  const int b    = blockIdx.y;
  const int tid  = threadIdx.x;
  const int h    = tid >> 6;
  const int lane = tid & 63;
  const int quad = lane >> 4;
  const int l16  = lane & 15;
  const int q0   = qt * 32;

  __shared__ u16 sc[16][32][40];  // 40KB; scores then (in-place) attn, bf16

  bf16x8 qf[2][2];
  {
    const u16* Qb = Qg + ((size_t)(b * S_ + q0)) * D_ + h * E_;
#pragma unroll
    for (int i = 0; i < 2; ++i)
#pragma unroll
      for (int c = 0; c < 2; ++c)
        qf[i][c] = *(const bf16x8*)(Qb + (size_t)(i * 16 + l16) * D_ +
                                    c * 32 + quad * 8);
  }

  f32x4 oacc[2][4];
#pragma unroll
  for (int i = 0; i < 2; ++i)
#pragma unroll
    for (int nc = 0; nc < 4; ++nc) oacc[i][nc] = (f32x4){0.f, 0.f, 0.f, 0.f};

  const float rsq8 = sqrtf(8.0f);

  for (int kt = 0; kt < 32; ++kt) {
    const int k0 = kt * 32;
    {  // ---- scores = Q K^T / sqrt(8), mask, -> LDS bf16 ----
      const u16* Kb = Kg + ((size_t)(b * S_ + k0)) * D_ + h * E_;
      bf16x8 kf[2][2];
#pragma unroll
      for (int nc = 0; nc < 2; ++nc)
#pragma unroll
        for (int c = 0; c < 2; ++c)
          kf[nc][c] = *(const bf16x8*)(Kb + (size_t)(nc * 16 + l16) * D_ +
                                       c * 32 + quad * 8);
      f32x4 sacc[2][2];
#pragma unroll
      for (int i = 0; i < 2; ++i)
#pragma unroll
        for (int nc = 0; nc < 2; ++nc) sacc[i][nc] = (f32x4){0.f,0.f,0.f,0.f};
#pragma unroll
      for (int c = 0; c < 2; ++c)
#pragma unroll
        for (int i = 0; i < 2; ++i)
#pragma unroll
          for (int nc = 0; nc < 2; ++nc)
            sacc[i][nc] = __builtin_amdgcn_mfma_f32_16x16x32_bf16(
                qf[i][c], kf[nc][c], sacc[i][nc], 0, 0, 0);
#pragma unroll
      for (int i = 0; i < 2; ++i)
#pragma unroll
        for (int nc = 0; nc < 2; ++nc)
#pragma unroll
          for (int reg = 0; reg < 4; ++reg) {
            int qrow = i * 16 + quad * 4 + reg;
            int kcol = nc * 16 + l16;
            float s = sacc[i][nc][reg] / rsq8;
            if ((k0 + kcol > q0 + qrow) || (s == 0.0f)) s = -1e9f;
            sc[h][qrow][kcol] = f2b(s);
          }
    }
    __syncthreads();
    {  // ---- softmax across the 16 heads at this thread's (q,k) ----
      const int qq = tid >> 5, kk = tid & 31;
      float v[16];
      float m = -3.0e38f;
#pragma unroll
      for (int hh = 0; hh < 16; ++hh) {
        v[hh] = b2f(sc[hh][qq][kk]);
        m = fmaxf(m, v[hh]);
      }
      float sum = 0.f;
#pragma unroll
      for (int hh = 0; hh < 16; ++hh) { v[hh] = expf(v[hh] - m); sum += v[hh]; }
#pragma unroll
      for (int hh = 0; hh < 16; ++hh) sc[hh][qq][kk] = f2b(v[hh] / sum);
    }
    __syncthreads();
    {  // ---- O += attn @ V ----
      bf16x8 af[2];
#pragma unroll
      for (int i = 0; i < 2; ++i)
        af[i] = *(const bf16x8*)(&sc[h][i * 16 + l16][quad * 8]);
      const u16* Vb = Vt + ((size_t)((b * H_ + h) * E_)) * S_ + k0;
      bf16x8 vf[4];
#pragma unroll
      for (int nc = 0; nc < 4; ++nc)
        vf[nc] = *(const bf16x8*)(Vb + (size_t)(nc * 16 + l16) * S_ + quad * 8);
#pragma unroll
      for (int i = 0; i < 2; ++i)
#pragma unroll
        for (int nc = 0; nc < 4; ++nc)
          oacc[i][nc] = __builtin_amdgcn_mfma_f32_16x16x32_bf16(
              af[i], vf[nc], oacc[i][nc], 0, 0, 0);
    }
    __syncthreads();
  }

  u16* Ob = AO + ((size_t)(b * S_ + q0)) * D_ + h * E_;
#pragma unroll
  for (int i = 0; i < 2; ++i)
#pragma unroll
    for (int nc = 0; nc < 4; ++nc)
#pragma unroll
      for (int reg = 0; reg < 4; ++reg) {
        int qrow = i * 16 + quad * 4 + reg;
        int e    = nc * 16 + l16;
        Ob[(size_t)qrow * D_ + e] = f2b(oacc[i][nc][reg]);
      }
}

// ---------------------------------------------------------------------------
extern "C" void kernel_launch(void* const* d_in, const int* in_sizes, int n_in,
                              void* d_out, int out_size, void* d_ws,
                              size_t ws_size, hipStream_t stream)
{
  const float* X1 = (const float*)d_in[0];
  const float* X2 = (const float*)d_in[1];
  const float* Wq = (const float*)d_in[2];
  const float* bq = (const float*)d_in[3];
  const float* Wk = (const float*)d_in[4];
  const float* bk = (const float*)d_in[5];
  const float* Wv = (const float*)d_in[6];
  const float* bv = (const float*)d_in[7];
  const float* Wo = (const float*)d_in[8];
  const float* bo = (const float*)d_in[9];

  // Workspace (u16 units): X1b,X2b 8M each; Wt 1M x4; Qb,Kb,Vb,Vtb 8M each.
  // AO aliases Vb (dead after transpose_v). Total 44M u16 = 88MB.
  u16* X1b = (u16*)d_ws;
  u16* X2b = X1b + (8u << 20);
  u16* WtQ = X2b + (8u << 20);
  u16* WtK = WtQ + (1u << 20);
  u16* WtV = WtK + (1u << 20);
  u16* WtO = WtV + (1u << 20);
  u16* Qb  = WtO + (1u << 20);
  u16* Kb  = Qb + (8u << 20);
  u16* Vb  = Kb + (8u << 20);
  u16* Vtb = Vb + (8u << 20);
  u16* AOb = Vb;  // alias

  cvt_bf16<<<4096, 256, 0, stream>>>(X1, X1b);
  cvt_bf16<<<4096, 256, 0, stream>>>(X2, X2b);

  dim3 tg(16, 16);
  trans_cvt_w<<<tg, 256, 0, stream>>>(Wq, WtQ);
  trans_cvt_w<<<tg, 256, 0, stream>>>(Wk, WtK);
  trans_cvt_w<<<tg, 256, 0, stream>>>(Wv, WtV);
  trans_cvt_w<<<tg, 256, 0, stream>>>(Wo, WtO);

  dim3 gg(64, 8);  // (M/128, N/128)
  gemm_bf16<<<gg, 256, 0, stream>>>(X1b, WtQ, bq, Qb, 8192, 1024, 1024, 0);
  gemm_bf16<<<gg, 256, 0, stream>>>(X2b, WtK, bk, Kb, 8192, 1024, 1024, 0);
  gemm_bf16<<<gg, 256, 0, stream>>>(X2b, WtV, bv, Vb, 8192, 1024, 1024, 0);

  transpose_v<<<dim3(16, 128), 256, 0, stream>>>(Vb, Vtb);

  attn_headsoftmax<<<dim3(32, 8), 1024, 0, stream>>>(Qb, Kb, Vtb, AOb);

  // Output fp32 (reference returns float32).
  gemm_bf16<<<gg, 256, 0, stream>>>(AOb, WtO, bo, d_out, 8192, 1024, 1024, 1);
}

// Round 7
// 439.058 us; speedup vs baseline: 32.3847x; 1.2137x over previous
//
#include <hip/hip_runtime.h>
#include <cstdint>

// ---------------------------------------------------------------------------
// MultiHeadAttention (B=8,S=1024,D=1024,H=16,E=64). Inputs fp32, output fp32.
// Quirks: scale = 1/sqrt(8) (d_k = batch quirk); tril + exact-zero -> -1e9
// (fp32, pre-round); softmax over HEADS axis (local per (b,q,k)).
//
// R7: (1) attention VALU strength-reduction — __expf, reciprocal-multiply
// instead of 32 divides/thread/iter, fp32 scores in LDS (no bf16 round-trip;
// closer to ref), bf16 only for the PV attn fragments. (2) gemm_bf16 staging
// via global_load_lds width=16 (m97 ladder; R1's NaN was input dtype, not
// this path — address shape is wave-uniform base + lane*16).
// ---------------------------------------------------------------------------

typedef unsigned short u16;
typedef unsigned int   u32;
typedef __attribute__((ext_vector_type(8))) __bf16         bf16x8;
typedef __attribute__((ext_vector_type(8))) unsigned short ushort8;
typedef __attribute__((ext_vector_type(4))) float          f32x4;

#define S_ 1024
#define D_ 1024
#define H_ 16
#define E_ 64

__device__ __forceinline__ float b2f(u16 h) {
  union { u32 u; float f; } v; v.u = ((u32)h) << 16; return v.f;
}
__device__ __forceinline__ u16 f2b(float f) {      // round-to-nearest-even
  union { float f; u32 u; } v; v.f = f;
  u32 r = v.u + 0x7fffu + ((v.u >> 16) & 1u);
  return (u16)(r >> 16);
}

typedef const __attribute__((address_space(1))) u32 gu32;
typedef       __attribute__((address_space(3))) u32 lu32;

// 16B global->LDS direct load; LDS dest must be wave-uniform base + lane*16.
__device__ __forceinline__ void gload_lds16(const u16* g, u16* l) {
  __builtin_amdgcn_global_load_lds((gu32*)(uintptr_t)g, (lu32*)(uintptr_t)l,
                                   16, 0, 0);
}

// ---------------------------------------------------------------------------
// fp32 -> bf16 elementwise convert (n = multiple of 2048).
// ---------------------------------------------------------------------------
__global__ __launch_bounds__(256, 1) void cvt_bf16(
    const float* __restrict__ src, u16* __restrict__ dst)
{
  const size_t i = (size_t)blockIdx.x * 256 + threadIdx.x;
  float4 a = ((const float4*)src)[2 * i];
  float4 b = ((const float4*)src)[2 * i + 1];
  ushort8 o;
  o[0] = f2b(a.x); o[1] = f2b(a.y); o[2] = f2b(a.z); o[3] = f2b(a.w);
  o[4] = f2b(b.x); o[5] = f2b(b.y); o[6] = f2b(b.z); o[7] = f2b(b.w);
  ((ushort8*)dst)[i] = o;
}

// ---------------------------------------------------------------------------
// Weight transpose+convert: W fp32 [K][N] -> Wt bf16 [N][K]. 64x64 tiles.
// ---------------------------------------------------------------------------
__global__ __launch_bounds__(256, 1) void trans_cvt_w(
    const float* __restrict__ W, u16* __restrict__ Wt)
{
  __shared__ u16 t[64][72];
  const int k0 = blockIdx.x * 64, n0 = blockIdx.y * 64;
  const int row = threadIdx.x >> 3;
  const int cs  = (threadIdx.x & 7) * 8;
#pragma unroll
  for (int p = 0; p < 2; ++p) {
    int r = row + p * 32;
    const float* Wp = W + (size_t)(k0 + r) * 1024 + n0 + cs;
    float4 a = *(const float4*)(Wp);
    float4 b = *(const float4*)(Wp + 4);
    u16* tp = &t[r][cs];
    tp[0] = f2b(a.x); tp[1] = f2b(a.y); tp[2] = f2b(a.z); tp[3] = f2b(a.w);
    tp[4] = f2b(b.x); tp[5] = f2b(b.y); tp[6] = f2b(b.z); tp[7] = f2b(b.w);
  }
  __syncthreads();
#pragma unroll
  for (int p = 0; p < 2; ++p) {
    int n = row + p * 32;
    ushort8 v;
#pragma unroll
    for (int i = 0; i < 8; ++i) v[i] = t[cs + i][n];
    *(ushort8*)(Wt + (size_t)(n0 + n) * 1024 + k0 + cs) = v;
  }
}

// ---------------------------------------------------------------------------
// bf16 MFMA GEMM: C[M][N] = A[M][K] @ Bt[N][K]^T + bias[N] (fp32 accum).
// 128x128 tile, BK=32, 256 threads / 4 waves. m97-style global_load_lds
// width-16 staging. out_f32: 1 -> fp32 stores, 0 -> bf16 stores.
// ---------------------------------------------------------------------------
__global__ __launch_bounds__(256, 1) void gemm_bf16(
    const u16* __restrict__ A, const u16* __restrict__ Bt,
    const float* __restrict__ bias, void* __restrict__ Cv,
    int M, int N, int K, int out_f32)
{
  __shared__ u16 As[128 * 32];   // [m][k] row-major, 8KB
  __shared__ u16 Bs[128 * 32];   // [n][k] row-major, 8KB
  const int tid  = threadIdx.x;
  const int wave = tid >> 6;
  const int lane = tid & 63;
  const int quad = lane >> 4;
  const int l16  = lane & 15;
  const int m0   = (wave & 1) * 64;
  const int n0   = (wave >> 1) * 64;

  const u16* Ab = A  + (size_t)blockIdx.x * 128 * K;
  const u16* Bb = Bt + (size_t)blockIdx.y * 128 * K;

  f32x4 acc[4][4];
#pragma unroll
  for (int i = 0; i < 4; ++i)
#pragma unroll
    for (int j = 0; j < 4; ++j) acc[i][j] = (f32x4){0.f, 0.f, 0.f, 0.f};

  for (int kb = 0; kb < K; kb += 32) {
    __syncthreads();               // prior iter's LDS reads done
#pragma unroll
    for (int p = 0; p < 2; ++p) {  // 512 16B segs over 256 threads
      int seg = tid + p * 256;     // = (wave*64+p*256) + lane -> base+lane*16
      int row = seg >> 2, ks = seg & 3;
      gload_lds16(Ab + (size_t)row * K + kb + ks * 8, As + seg * 8);
      gload_lds16(Bb + (size_t)row * K + kb + ks * 8, Bs + seg * 8);
    }
    __builtin_amdgcn_s_waitcnt(0); // drain vmcnt before barrier
    __syncthreads();

    bf16x8 af[4], bfr[4];
#pragma unroll
    for (int i = 0; i < 4; ++i)    // A-frag: m=lane&15, k=quad*8+j
      af[i] = *(const bf16x8*)(As + (m0 + i * 16 + l16) * 32 + quad * 8);
#pragma unroll
    for (int j = 0; j < 4; ++j)    // B-frag: n=lane&15, k=quad*8+j
      bfr[j] = *(const bf16x8*)(Bs + (n0 + j * 16 + l16) * 32 + quad * 8);
#pragma unroll
    for (int i = 0; i < 4; ++i)
#pragma unroll
      for (int j = 0; j < 4; ++j)
        acc[i][j] = __builtin_amdgcn_mfma_f32_16x16x32_bf16(
            af[i], bfr[j], acc[i][j], 0, 0, 0);
  }

  float bv[4];
#pragma unroll
  for (int j = 0; j < 4; ++j)
    bv[j] = bias[(size_t)blockIdx.y * 128 + n0 + j * 16 + l16];

  if (out_f32) {
    float* C = (float*)Cv;
#pragma unroll
    for (int i = 0; i < 4; ++i) {
      int r = blockIdx.x * 128 + m0 + i * 16 + quad * 4;   // row=quad*4+reg
#pragma unroll
      for (int j = 0; j < 4; ++j) {
        int c = blockIdx.y * 128 + n0 + j * 16 + l16;      // col=lane&15
#pragma unroll
        for (int reg = 0; reg < 4; ++reg)
          C[(size_t)(r + reg) * N + c] = acc[i][j][reg] + bv[j];
      }
    }
  } else {
    u16* C = (u16*)Cv;
#pragma unroll
    for (int i = 0; i < 4; ++i) {
      int r = blockIdx.x * 128 + m0 + i * 16 + quad * 4;
#pragma unroll
      for (int j = 0; j < 4; ++j) {
        int c = blockIdx.y * 128 + n0 + j * 16 + l16;
#pragma unroll
        for (int reg = 0; reg < 4; ++reg)
          C[(size_t)(r + reg) * N + c] = f2b(acc[i][j][reg] + bv[j]);
      }
    }
  }
}

// ---------------------------------------------------------------------------
// V transpose (bf16): V[b][s][h*64+e] -> Vt[(b*16+h)*64+e][s]  (per-head E,S)
// ---------------------------------------------------------------------------
__global__ __launch_bounds__(256, 1) void transpose_v(
    const u16* __restrict__ V, u16* __restrict__ Vt)
{
  __shared__ u16 t[64][72];
  const int s0 = blockIdx.x * 64;
  const int bh = blockIdx.y;           // b*16 + h
  const int b = bh >> 4, h = bh & 15;
  const int row = threadIdx.x >> 3;
  const int cs  = (threadIdx.x & 7) * 8;
#pragma unroll
  for (int p = 0; p < 2; ++p) {
    int s = row + p * 32;
    *(ushort8*)(&t[s][cs]) = *(const ushort8*)(
        V + ((size_t)(b * S_ + s0 + s)) * D_ + h * E_ + cs);
  }
  __syncthreads();
#pragma unroll
  for (int p = 0; p < 2; ++p) {
    int e = row + p * 32;
    ushort8 v;
#pragma unroll
    for (int i = 0; i < 8; ++i) v[i] = t[cs + i][e];
    *(ushort8*)(Vt + ((size_t)(bh * E_ + e)) * S_ + s0 + cs) = v;
  }
}

// ---------------------------------------------------------------------------
// Fused attention, softmax over HEADS, bf16 MFMA.
// R7 changes: fp32 scores in LDS (no bf16 round-trip; ref-faithful), __expf,
// reciprocal-multiply softmax, bf16 attn buffer only for PV A-frags.
// LDS: scf 16*32*33*4 = 67.6KB + at 16*32*40*2 = 41KB -> 108.5KB (1 blk/CU).
// ---------------------------------------------------------------------------
__global__ __launch_bounds__(1024, 4) void attn_headsoftmax(
    const u16* __restrict__ Qg,   // [B][S][D] bf16
    const u16* __restrict__ Kg,   // [B][S][D] bf16
    const u16* __restrict__ Vt,   // [B*H][E][S] bf16
    u16* __restrict__ AO)         // [B][S][D] bf16
{
  const int qt   = blockIdx.x;
  const int b    = blockIdx.y;
  const int tid  = threadIdx.x;
  const int h    = tid >> 6;
  const int lane = tid & 63;
  const int quad = lane >> 4;
  const int l16  = lane & 15;
  const int q0   = qt * 32;

  __shared__ float scf[16][32][33];  // fp32 scores (odd stride, 2-way free)
  __shared__ u16   at[16][32][40];   // bf16 attn for PV A-frags

  bf16x8 qf[2][2];
  {
    const u16* Qb = Qg + ((size_t)(b * S_ + q0)) * D_ + h * E_;
#pragma unroll
    for (int i = 0; i < 2; ++i)
#pragma unroll
      for (int c = 0; c < 2; ++c)
        qf[i][c] = *(const bf16x8*)(Qb + (size_t)(i * 16 + l16) * D_ +
                                    c * 32 + quad * 8);
  }

  f32x4 oacc[2][4];
#pragma unroll
  for (int i = 0; i < 2; ++i)
#pragma unroll
    for (int nc = 0; nc < 4; ++nc) oacc[i][nc] = (f32x4){0.f, 0.f, 0.f, 0.f};

  // 1/sqrt(8), correctly rounded fp32; <=1ulp vs the ref's true division,
  // and s==0 <=> dot==0 under both forms (the quirk check is unaffected).
  const float inv_rsq8 = 0.35355339059327373f;

  for (int kt = 0; kt < 32; ++kt) {
    const int k0 = kt * 32;
    {  // ---- scores = Q K^T * (1/sqrt8), mask, -> LDS fp32 ----
      const u16* Kb = Kg + ((size_t)(b * S_ + k0)) * D_ + h * E_;
      bf16x8 kf[2][2];
#pragma unroll
      for (int nc = 0; nc < 2; ++nc)
#pragma unroll
        for (int c = 0; c < 2; ++c)
          kf[nc][c] = *(const bf16x8*)(Kb + (size_t)(nc * 16 + l16) * D_ +
                                       c * 32 + quad * 8);
      f32x4 sacc[2][2];
#pragma unroll
      for (int i = 0; i < 2; ++i)
#pragma unroll
        for (int nc = 0; nc < 2; ++nc) sacc[i][nc] = (f32x4){0.f,0.f,0.f,0.f};
#pragma unroll
      for (int c = 0; c < 2; ++c)
#pragma unroll
        for (int i = 0; i < 2; ++i)
#pragma unroll
          for (int nc = 0; nc < 2; ++nc)
            sacc[i][nc] = __builtin_amdgcn_mfma_f32_16x16x32_bf16(
                qf[i][c], kf[nc][c], sacc[i][nc], 0, 0, 0);
#pragma unroll
      for (int i = 0; i < 2; ++i)
#pragma unroll
        for (int nc = 0; nc < 2; ++nc)
#pragma unroll
          for (int reg = 0; reg < 4; ++reg) {
            int qrow = i * 16 + quad * 4 + reg;  // C: row=quad*4+reg
            int kcol = nc * 16 + l16;            // C: col=lane&15
            float s = sacc[i][nc][reg] * inv_rsq8;
            if ((k0 + kcol > q0 + qrow) || (s == 0.0f)) s = -1e9f;
            scf[h][qrow][kcol] = s;
          }
    }
    __syncthreads();
    {  // ---- softmax across 16 heads at this thread's (q,k) ----
      const int qq = tid >> 5, kk = tid & 31;
      float v[16];
      float m = -3.0e38f;
#pragma unroll
      for (int hh = 0; hh < 16; ++hh) {
        v[hh] = scf[hh][qq][kk];
        m = fmaxf(m, v[hh]);
      }
      float sum = 0.f;
#pragma unroll
      for (int hh = 0; hh < 16; ++hh) {
        v[hh] = __expf(v[hh] - m);   // fast exp; exp(0)=1, exp(-1e9)=0 exact
        sum += v[hh];
      }
      float inv = 1.0f / sum;        // all-masked: 1/16 (pow2) -> exact
#pragma unroll
      for (int hh = 0; hh < 16; ++hh) at[hh][qq][kk] = f2b(v[hh] * inv);
    }
    __syncthreads();
    {  // ---- O += attn @ V ----
      bf16x8 af[2];
#pragma unroll
      for (int i = 0; i < 2; ++i)    // A: m=q (lane&15), k=s (quad*8+j)
        af[i] = *(const bf16x8*)(&at[h][i * 16 + l16][quad * 8]);
      const u16* Vb = Vt + ((size_t)((b * H_ + h) * E_)) * S_ + k0;
      bf16x8 vf[4];
#pragma unroll
      for (int nc = 0; nc < 4; ++nc) // B: n=e (lane&15), k=s (quad*8+j)
        vf[nc] = *(const bf16x8*)(Vb + (size_t)(nc * 16 + l16) * S_ + quad * 8);
#pragma unroll
      for (int i = 0; i < 2; ++i)
#pragma unroll
        for (int nc = 0; nc < 4; ++nc)
          oacc[i][nc] = __builtin_amdgcn_mfma_f32_16x16x32_bf16(
              af[i], vf[nc], oacc[i][nc], 0, 0, 0);
    }
    __syncthreads();
  }

  u16* Ob = AO + ((size_t)(b * S_ + q0)) * D_ + h * E_;
#pragma unroll
  for (int i = 0; i < 2; ++i)
#pragma unroll
    for (int nc = 0; nc < 4; ++nc)
#pragma unroll
      for (int reg = 0; reg < 4; ++reg) {
        int qrow = i * 16 + quad * 4 + reg;
        int e    = nc * 16 + l16;
        Ob[(size_t)qrow * D_ + e] = f2b(oacc[i][nc][reg]);
      }
}

// ---------------------------------------------------------------------------
extern "C" void kernel_launch(void* const* d_in, const int* in_sizes, int n_in,
                              void* d_out, int out_size, void* d_ws,
                              size_t ws_size, hipStream_t stream)
{
  const float* X1 = (const float*)d_in[0];
  const float* X2 = (const float*)d_in[1];
  const float* Wq = (const float*)d_in[2];
  const float* bq = (const float*)d_in[3];
  const float* Wk = (const float*)d_in[4];
  const float* bk = (const float*)d_in[5];
  const float* Wv = (const float*)d_in[6];
  const float* bv = (const float*)d_in[7];
  const float* Wo = (const float*)d_in[8];
  const float* bo = (const float*)d_in[9];

  // Workspace (u16 units): X1b,X2b 8M; Wt 1M x4; Qb,Kb,Vb,Vtb 8M. AO aliases
  // Vb (dead after transpose_v). Total 44M u16 = 88MB.
  u16* X1b = (u16*)d_ws;
  u16* X2b = X1b + (8u << 20);
  u16* WtQ = X2b + (8u << 20);
  u16* WtK = WtQ + (1u << 20);
  u16* WtV = WtK + (1u << 20);
  u16* WtO = WtV + (1u << 20);
  u16* Qb  = WtO + (1u << 20);
  u16* Kb  = Qb + (8u << 20);
  u16* Vb  = Kb + (8u << 20);
  u16* Vtb = Vb + (8u << 20);
  u16* AOb = Vb;  // alias

  cvt_bf16<<<4096, 256, 0, stream>>>(X1, X1b);
  cvt_bf16<<<4096, 256, 0, stream>>>(X2, X2b);

  dim3 tg(16, 16);
  trans_cvt_w<<<tg, 256, 0, stream>>>(Wq, WtQ);
  trans_cvt_w<<<tg, 256, 0, stream>>>(Wk, WtK);
  trans_cvt_w<<<tg, 256, 0, stream>>>(Wv, WtV);
  trans_cvt_w<<<tg, 256, 0, stream>>>(Wo, WtO);

  dim3 gg(64, 8);  // (M/128, N/128)
  gemm_bf16<<<gg, 256, 0, stream>>>(X1b, WtQ, bq, Qb, 8192, 1024, 1024, 0);
  gemm_bf16<<<gg, 256, 0, stream>>>(X2b, WtK, bk, Kb, 8192, 1024, 1024, 0);
  gemm_bf16<<<gg, 256, 0, stream>>>(X2b, WtV, bv, Vb, 8192, 1024, 1024, 0);

  transpose_v<<<dim3(16, 128), 256, 0, stream>>>(Vb, Vtb);

  attn_headsoftmax<<<dim3(32, 8), 1024, 0, stream>>>(Qb, Kb, Vtb, AOb);

  // Output fp32 (reference returns float32).
  gemm_bf16<<<gg, 256, 0, stream>>>(AOb, WtO, bo, d_out, 8192, 1024, 1024, 1);
}